// Round 1
// baseline (3122.724 us; speedup 1.0000x reference)
//
#include <hip/hip_runtime.h>

#define NN 1024
#define NW 32   // 32-bit words per ancestor bitset row

__global__ void zero_out_kernel(float4* __restrict__ out) {
    int idx = blockIdx.x * blockDim.x + threadIdx.x;
    out[idx] = make_float4(0.f, 0.f, 0.f, 0.f);
}

__global__ __launch_bounds__(1024) void dag_bfs_kernel(
    const float* __restrict__ root_probs,
    const float* __restrict__ edge_probs,
    const float* __restrict__ g_roots,
    const float* __restrict__ g_edges,
    float* __restrict__ out)
{
    extern __shared__ unsigned int smem[];
    unsigned int* anc     = smem;                         // NN*NW words (128 KiB)
    unsigned int* ancI    = anc + NN * NW;                // NW words
    int*          queue   = (int*)(ancI + NW);            // NN ints
    int*          wavecnt = queue + NN;                   // 16 ints
    int*          ctrl    = wavecnt + 16;                 // [0]=head [1]=tail
    unsigned char* notroot = (unsigned char*)(ctrl + 4);  // NN bytes
    unsigned char* inq     = notroot + NN;                // NN bytes

    const int tid  = threadIdx.x;
    const int lane = tid & 63;
    const int wid  = tid >> 6;

    // ---- init ancestor bitset: anc[j] = {j} ----
    #pragma unroll
    for (int k = 0; k < NW; ++k) {
        int w = (tid + k) & (NW - 1);           // rotated: distinct banks per lane
        anc[tid * NW + w] = (w == (tid >> 5)) ? (1u << (tid & 31)) : 0u;
    }

    // ---- roots ----
    float rp = root_probs[tid];
    float2 gr = reinterpret_cast<const float2*>(g_roots)[tid];
    bool root = (rp + gr.x) > ((1.0f - rp) + gr.y);   // exact IEEE f32, matches JAX
    notroot[tid] = root ? 0 : 1;
    inq[tid]     = root ? 1 : 0;

    unsigned long long m0 = __ballot(root ? 1 : 0);
    int lp0 = __popcll(m0 & ((1ULL << lane) - 1ULL));
    if (lane == 0) wavecnt[wid] = __popcll(m0);
    __syncthreads();
    int off0 = 0, tot0 = 0;
    #pragma unroll
    for (int w2 = 0; w2 < 16; ++w2) {
        int c = wavecnt[w2];
        off0 += (w2 < wid) ? c : 0;
        tot0 += c;
    }
    if (root) queue[off0 + lp0] = tid;   // roots in ascending order
    if (tid == 0) { ctrl[0] = 0; ctrl[1] = tot0; }
    __syncthreads();

    // ---- sequential BFS ----
    for (;;) {
        int head = ctrl[0];
        int tail = ctrl[1];
        if (head >= tail) break;
        int i = queue[head];

        // global loads for row i (coalesced; issue before the barrier)
        float  p = edge_probs[i * NN + tid];
        float2 g = reinterpret_cast<const float2*>(g_edges)[i * NN + tid];
        if (tid < NW) ancI[tid] = anc[i * NW + tid];
        __syncthreads();                       // ancI ready

        bool hard = (p + g.x) > ((1.0f - p) + g.y);
        bool abit = (ancI[tid >> 5] >> (tid & 31)) & 1u;
        bool hit  = hard && (notroot[tid] != 0) && !abit;

        out[i * NN + tid] = hit ? 1.0f : 0.0f;

        if (hit) {
            #pragma unroll
            for (int k = 0; k < NW; ++k) {
                int w = (tid + k) & (NW - 1);  // rotated: conflict-light
                anc[tid * NW + w] |= ancI[w];
            }
        }

        bool newf = hit && (inq[tid] == 0);
        if (newf) inq[tid] = 1;

        unsigned long long m = __ballot(newf ? 1 : 0);
        int lp = __popcll(m & ((1ULL << lane) - 1ULL));
        if (lane == 0) wavecnt[wid] = __popcll(m);
        __syncthreads();                       // wavecnt ready; anc updates done

        int off = 0, total = 0;
        #pragma unroll
        for (int w2 = 0; w2 < 16; ++w2) {
            int c = wavecnt[w2];
            off   += (w2 < wid) ? c : 0;
            total += c;
        }
        if (newf) queue[tail + off + lp] = tid;  // ascending-j append
        if (tid == 0) { ctrl[0] = head + 1; ctrl[1] = tail + total; }
        __syncthreads();                       // queue/ctrl visible next iter
    }
}

extern "C" void kernel_launch(void* const* d_in, const int* in_sizes, int n_in,
                              void* d_out, int out_size, void* d_ws, size_t ws_size,
                              hipStream_t stream) {
    const float* root_probs = (const float*)d_in[0];
    const float* edge_probs = (const float*)d_in[1];
    const float* g_roots    = (const float*)d_in[2];
    const float* g_edges    = (const float*)d_in[3];
    float* out = (float*)d_out;

    // zero all of d_out (harness poisons with 0xAA); BFS overwrites processed rows
    zero_out_kernel<<<NN * NN / 4 / 256, 256, 0, stream>>>((float4*)out);

    // dynamic LDS: anc(128K) + ancI + queue + wavecnt + ctrl + notroot + inq
    size_t lds = (size_t)NN * NW * 4 + NW * 4 + NN * 4 + 16 * 4 + 4 * 4 + NN + NN;
    hipFuncSetAttribute((const void*)dag_bfs_kernel,
                        hipFuncAttributeMaxDynamicSharedMemorySize, (int)lds);
    dag_bfs_kernel<<<1, NN, lds, stream>>>(root_probs, edge_probs, g_roots, g_edges, out);
}

// Round 2
// 895.692 us; speedup vs baseline: 3.4864x; 3.4864x over previous
//
#include <hip/hip_runtime.h>

#define NN 1024
#define NW 32   // 32-bit words per row bitset

// ---- Kernel A: edge float data -> hard-decision bit matrix E[NN][NW] ----
__global__ void edge_bits_kernel(const float* __restrict__ ep,
                                 const float* __restrict__ ge,
                                 unsigned* __restrict__ E) {
    int idx = blockIdx.x * blockDim.x + threadIdx.x;   // element (i*NN + j)
    float  p = ep[idx];
    float2 g = reinterpret_cast<const float2*>(ge)[idx];
    bool hard = (p + g.x) > ((1.0f - p) + g.y);        // exact IEEE f32
    unsigned long long m = __ballot(hard);
    int lane = threadIdx.x & 63;
    if ((lane & 31) == 0)
        E[idx >> 5] = (unsigned)(m >> (lane & 32));    // global word = i*32 + j/32
}

// ---- Kernel B: serial BFS entirely on bitsets; anc rows live in registers ----
__global__ __launch_bounds__(1024) void dag_bfs_bits(
    const float* __restrict__ root_probs,
    const float* __restrict__ g_roots,
    const unsigned* __restrict__ E,
    unsigned* __restrict__ dagbits)
{
    __shared__ unsigned ancI[NW];     // published anc row of current node i
    __shared__ int queue[NN];
    __shared__ int wavecnt[16];

    const int tid  = threadIdx.x;
    const int lane = tid & 63;
    const int wid  = tid >> 6;
    const int      myw   = tid >> 5;
    const unsigned mybit = 1u << (tid & 31);

    // ancestor row of node `tid` in registers (32 words); statically indexed only
    unsigned ancreg[NW];
    #pragma unroll
    for (int k = 0; k < NW; ++k) ancreg[k] = (k == myw) ? mybit : 0u;

    float  rp = root_probs[tid];
    float2 gr = reinterpret_cast<const float2*>(g_roots)[tid];
    bool root     = (rp + gr.x) > ((1.0f - rp) + gr.y);
    bool notroot  = !root;
    bool inq      = root;
    bool processed = false;

    // seed queue with roots in ascending order
    unsigned long long m0 = __ballot(root);
    int lp0 = __popcll(m0 & ((1ULL << lane) - 1ULL));
    if (lane == 0) wavecnt[wid] = __popcll(m0);
    __syncthreads();
    int head = 0, tail = 0, off0 = 0;
    #pragma unroll
    for (int w = 0; w < 16; ++w) { int c = wavecnt[w]; if (w < wid) off0 += c; tail += c; }
    if (root) queue[off0 + lp0] = tid;
    __syncthreads();

    while (head < tail) {
        int i = queue[head];                          // stable since last barrier
        unsigned eword = E[i * NW + myw];             // issue early; L2-resident

        if (tid == i) {
            processed = true;
            #pragma unroll
            for (int k = 0; k < NW; ++k) ancI[k] = ancreg[k];
        }
        __syncthreads();                              // ancI published

        bool abit = (ancI[myw] & mybit) != 0;
        bool hit  = ((eword & mybit) != 0) && notroot && !abit;

        // dag row i as bits (ballot across each wave -> 2 words/wave)
        unsigned long long hm = __ballot(hit);
        if ((lane & 31) == 0)
            dagbits[i * NW + (tid >> 5)] = (unsigned)(hm >> (lane & 32));

        bool newf = hit && !inq;
        inq |= newf;
        unsigned long long nm = __ballot(newf);
        int lp = __popcll(nm & ((1ULL << lane) - 1ULL));
        if (lane == 0) wavecnt[wid] = __popcll(nm);

        // anc[j] |= anc[i] — only matters for not-yet-processed j
        if (hit && !processed) {
            #pragma unroll
            for (int k = 0; k < NW; ++k) ancreg[k] |= ancI[k];
        }
        __syncthreads();                              // wavecnt ready
        int off = 0, tot = 0;
        #pragma unroll
        for (int w = 0; w < 16; ++w) { int c = wavecnt[w]; if (w < wid) off += c; tot += c; }
        if (newf) queue[tail + off + lp] = tid;       // ascending-j append
        head += 1; tail += tot;
        __syncthreads();                              // queue writes visible
    }
}

// ---- Kernel C: dag bits -> f32 output (also covers zero rows) ----
__global__ void expand_kernel(const unsigned* __restrict__ dagbits,
                              float4* __restrict__ out) {
    int idx = blockIdx.x * blockDim.x + threadIdx.x;  // one float4 (4 bits)
    unsigned w = dagbits[idx >> 3];
    int b = (idx & 7) * 4;
    float4 o;
    o.x = (w >> (b + 0)) & 1 ? 1.0f : 0.0f;
    o.y = (w >> (b + 1)) & 1 ? 1.0f : 0.0f;
    o.z = (w >> (b + 2)) & 1 ? 1.0f : 0.0f;
    o.w = (w >> (b + 3)) & 1 ? 1.0f : 0.0f;
    out[idx] = o;
}

extern "C" void kernel_launch(void* const* d_in, const int* in_sizes, int n_in,
                              void* d_out, int out_size, void* d_ws, size_t ws_size,
                              hipStream_t stream) {
    const float* root_probs = (const float*)d_in[0];
    const float* edge_probs = (const float*)d_in[1];
    const float* g_roots    = (const float*)d_in[2];
    const float* g_edges    = (const float*)d_in[3];

    unsigned* E       = (unsigned*)d_ws;          // 128 KiB
    unsigned* dagbits = E + NN * NW;              // 128 KiB

    hipMemsetAsync(dagbits, 0, (size_t)NN * NW * sizeof(unsigned), stream);
    edge_bits_kernel<<<NN * NN / 256, 256, 0, stream>>>(edge_probs, g_edges, E);
    dag_bfs_bits<<<1, NN, 0, stream>>>(root_probs, g_roots, E, dagbits);
    expand_kernel<<<NN * NN / 4 / 256, 256, 0, stream>>>(dagbits, (float4*)d_out);
}